// Round 4
// baseline (2172.435 us; speedup 1.0000x reference)
//
#include <hip/hip_runtime.h>
#include <hip/hip_bf16.h>
#include <math.h>

// ---- problem constants ----
#define BATCH   8
#define C_IN    3
#define IMG_SZ  224
#define P_SZ    16
#define NPATCH  196                 // (224/16)^2
#define MSEQ    197                 // NPATCH + cls
#define DDIM    192
#define EDIM    384
#define NSTATE  16
#define ENDIM   (EDIM*NSTATE)       // 6144
#define LLAYERS 2
#define ROWS    (BATCH*MSEQ)        // 1576
#define PROWS   (BATCH*NPATCH)      // 1568
#define PATCH_K (C_IN*P_SZ*P_SZ)    // 768

// precise silu (enters the scan only linearly)
__device__ __forceinline__ float silu_f(float x) { return x / (1.f + expf(-x)); }

// ------------------------------------------------------------------
// patchify: img (B,3,224,224) -> patches (PROWS, 768)
// ------------------------------------------------------------------
__global__ __launch_bounds__(256) void patchify_k(const float* __restrict__ img,
                                                  float* __restrict__ out) {
    int idx = blockIdx.x * 256 + threadIdx.x;
    if (idx >= PROWS * PATCH_K) return;
    int r = idx / PATCH_K, col = idx - r * PATCH_K;
    int b = r / NPATCH, p = r - b * NPATCH;
    int ph = p / 14, pw = p - ph * 14;
    int c = col >> 8, rem = col & 255, py = rem >> 4, px = rem & 15;
    out[idx] = img[((b * C_IN + c) * IMG_SZ + ph * P_SZ + py) * IMG_SZ + pw * P_SZ + px];
}

// ------------------------------------------------------------------
// assemble x = concat(cls, xemb) + pos   -> (B, MSEQ, DDIM)
// ------------------------------------------------------------------
__global__ __launch_bounds__(256) void assemble_k(const float* __restrict__ xemb,
                                                  const float* __restrict__ cls,
                                                  const float* __restrict__ pos,
                                                  float* __restrict__ x) {
    int idx = blockIdx.x * 256 + threadIdx.x;
    if (idx >= ROWS * DDIM) return;
    int d = idx % DDIM;
    int bm = idx / DDIM;
    int m = bm % MSEQ, b = bm / MSEQ;
    float v;
    if (m == 0) v = cls[d];
    else        v = xemb[((b * NPATCH) + (m - 1)) * DDIM + d];
    x[idx] = v + pos[m * DDIM + d];
}

// ------------------------------------------------------------------
// layernorm over last dim (DDIM=192), one wave per row
// ------------------------------------------------------------------
__global__ __launch_bounds__(256) void layernorm_k(const float* __restrict__ x,
                                                   const float* __restrict__ g,
                                                   const float* __restrict__ b,
                                                   float* __restrict__ o, int nrows) {
    int wave = threadIdx.x >> 6;
    int lane = threadIdx.x & 63;
    int row = blockIdx.x * 4 + wave;
    if (row >= nrows) return;
    const float* xr = x + (long)row * DDIM;
    float v0 = xr[lane], v1 = xr[lane + 64], v2 = xr[lane + 128];
    float s = v0 + v1 + v2;
    #pragma unroll
    for (int off = 1; off < 64; off <<= 1) s += __shfl_xor(s, off);
    float mu = s * (1.f / 192.f);
    float d0 = v0 - mu, d1 = v1 - mu, d2 = v2 - mu;
    float q = d0 * d0 + d1 * d1 + d2 * d2;
    #pragma unroll
    for (int off = 1; off < 64; off <<= 1) q += __shfl_xor(q, off);
    float inv = rsqrtf(q * (1.f / 192.f) + 1e-5f);
    float* orow = o + (long)row * DDIM;
    orow[lane]       = d0 * inv * g[lane]       + b[lane];
    orow[lane + 64]  = d1 * inv * g[lane + 64]  + b[lane + 64];
    orow[lane + 128] = d2 * inv * g[lane + 128] + b[lane + 128];
}

// ------------------------------------------------------------------
// generic fp32 GEMM: C[M,N] = A[M,K] @ W[K,N] + bias1 (+bias2) (+resid)
// ------------------------------------------------------------------
#define BM 128
#define BN 64
#define BK 16
__global__ __launch_bounds__(256) void gemm_k(const float* __restrict__ A,
                                              const float* __restrict__ W,
                                              const float* __restrict__ bias1,
                                              const float* __restrict__ bias2,
                                              const float* __restrict__ resid,
                                              float* __restrict__ C,
                                              int M, int N, int K) {
    __shared__ float As[BK][BM + 4];
    __shared__ float Ws[BK][BN];
    int t = threadIdx.x;
    int tx = t & 15, ty = t >> 4;
    int colBase = blockIdx.x * BN;
    int rowBase = blockIdx.y * BM;
    float acc[8][4] = {};
    int a_m = t >> 1, a_k = (t & 1) << 3;      // A: 2 float4 per thread
    int w_k = t >> 4, w_n = (t & 15) << 2;     // W: 1 float4 per thread
    for (int k0 = 0; k0 < K; k0 += BK) {
        int ar = rowBase + a_m;
        float4 av0 = make_float4(0.f, 0.f, 0.f, 0.f), av1 = av0;
        if (ar < M) {
            const float* ap = &A[(long)ar * K + k0 + a_k];
            av0 = *(const float4*)ap;
            av1 = *(const float4*)(ap + 4);
        }
        As[a_k + 0][a_m] = av0.x; As[a_k + 1][a_m] = av0.y;
        As[a_k + 2][a_m] = av0.z; As[a_k + 3][a_m] = av0.w;
        As[a_k + 4][a_m] = av1.x; As[a_k + 5][a_m] = av1.y;
        As[a_k + 6][a_m] = av1.z; As[a_k + 7][a_m] = av1.w;
        *(float4*)&Ws[w_k][w_n] = *(const float4*)&W[(long)(k0 + w_k) * N + colBase + w_n];
        __syncthreads();
        #pragma unroll
        for (int kk = 0; kk < BK; ++kk) {
            float4 a0 = *(const float4*)&As[kk][ty << 3];
            float4 a1 = *(const float4*)&As[kk][(ty << 3) + 4];
            float4 w  = *(const float4*)&Ws[kk][tx << 2];
            float ar8[8] = {a0.x, a0.y, a0.z, a0.w, a1.x, a1.y, a1.z, a1.w};
            float wr4[4] = {w.x, w.y, w.z, w.w};
            #pragma unroll
            for (int i = 0; i < 8; ++i)
                #pragma unroll
                for (int j = 0; j < 4; ++j) acc[i][j] += ar8[i] * wr4[j];
        }
        __syncthreads();
    }
    #pragma unroll
    for (int i = 0; i < 8; ++i) {
        int r = rowBase + (ty << 3) + i;
        if (r >= M) break;
        #pragma unroll
        for (int j = 0; j < 4; ++j) {
            int c = colBase + (tx << 2) + j;
            float v = acc[i][j] + bias1[c];
            if (bias2) v += bias2[c];
            if (resid) v += resid[(long)r * N + c];
            C[(long)r * N + c] = v;
        }
    }
}

// ------------------------------------------------------------------
// fused depthwise conv (fwd + bwd) + SiLU
// ------------------------------------------------------------------
__global__ __launch_bounds__(256) void dwconv_k(const float* __restrict__ xp,
                                                const float* __restrict__ wf,
                                                const float* __restrict__ bf,
                                                const float* __restrict__ wb,
                                                const float* __restrict__ bb,
                                                float* __restrict__ xf,
                                                float* __restrict__ xb) {
    int idx = blockIdx.x * 256 + threadIdx.x;
    if (idx >= ROWS * EDIM) return;
    int e = idx % EDIM;
    int bm = idx / EDIM;
    int m = bm % MSEQ, b = bm / MSEQ;
    const float* base = xp + (long)b * MSEQ * EDIM + e;
    float xm1 = (m > 0)        ? base[(m - 1) * EDIM] : 0.f;
    float x0  =                  base[m * EDIM];
    float xp1 = (m < MSEQ - 1) ? base[(m + 1) * EDIM] : 0.f;
    float f = wf[e * 3 + 0] * xm1 + wf[e * 3 + 1] * x0 + wf[e * 3 + 2] * xp1 + bf[e];
    float r = wb[e * 3 + 0] * xp1 + wb[e * 3 + 1] * x0 + wb[e * 3 + 2] * xm1 + bb[e];
    xf[idx] = silu_f(f);
    xb[idx] = silu_f(r);
}

// ------------------------------------------------------------------
// SSM recurrence — fp32 STORAGE semantics (matches an np-float32
// reference including P underflow at m~30), but every transcendental
// is CORRECTLY ROUNDED (computed in fp64, rounded to fp32). The
// clip-edge sites (|A| clipped to 1e-6, negative sign) amplify the
// last ulp of log/exp by ~1e12 via invP=1/(P+1e-6) cancellation —
// they depend ONLY on Apar and log2 (delta is exactly softplus(0)),
// so correctly-rounded log/exp is the entire fidelity game.
// fp contract OFF so the S/h chain rounds exactly like numpy.
// n-sum uses numpy's pairwise-16 order: xor8 first, then 1,2,4.
// ------------------------------------------------------------------
__global__ __launch_bounds__(256) void ssm_scan_k(const float* __restrict__ Bm,
                                                  const float* __restrict__ Cm,
                                                  const float* __restrict__ Dv,
                                                  const float* __restrict__ xs,
                                                  const float* __restrict__ Apar,
                                                  float* __restrict__ y) {
#pragma clang fp contract(off)
    int tid = blockIdx.x * 256 + threadIdx.x;    // B*E*N total = 49152
    int n = tid & (NSTATE - 1);
    int e = (tid / NSTATE) % EDIM;
    int b = tid / (EDIM * NSTATE);
    float Ap = Apar[e * NSTATE + n];
    float cumlog = 0.f, cumsign = 1.f, S = 0.f;
    int bcIdx = b * MSEQ * ENDIM + e * NSTATE + n;   // advances by ENDIM per m
    int dxIdx = b * MSEQ * EDIM + e;                 // advances by EDIM per m
    bool leader = ((threadIdx.x & 15) == 0);
    for (int m = 0; m < MSEQ; ++m) {
        float v = Dv[dxIdx];
        // softplus, correctly rounded to fp32
        double vd = (double)v;
        float delta = (float)(log1p(exp(-fabs(vd))) + fmax(vd, 0.0));
        float xv = xs[dxIdx];
        float Bv = Bm[bcIdx];
        float Cv = Cm[bcIdx];
        float A = delta * Ap;                              // exact fp32 product
        float sa = (A > 0.f) ? 1.f : ((A < 0.f) ? -1.f : 0.f);
        cumsign = cumsign * sa;
        float absA = fmaxf(fabsf(A), 1e-6f);
        float lg = (float)log((double)absA);               // CR fp32 log
        cumlog = cumlog + lg;                              // fp32 cumsum
        float ex = (float)exp((double)cumlog);             // CR fp32 exp
        float P = cumsign * ex;
        float t = P + 1e-6f;                               // exact near cancel
        float invP = 1.0f / t;                             // IEEE fp32 div
        float Bfull = delta * Bv;
        float t1 = invP * Bfull;
        float t2 = t1 * xv;
        S = S + t2;
        float h = P * S;
        float contrib = h * Cv;
        // numpy pairwise-16 reduction order
        contrib += __shfl_xor(contrib, 8);
        contrib += __shfl_xor(contrib, 1);
        contrib += __shfl_xor(contrib, 2);
        contrib += __shfl_xor(contrib, 4);
        if (leader) y[dxIdx] = contrib;
        bcIdx += ENDIM;
        dxIdx += EDIM;
    }
}

// ------------------------------------------------------------------
// combine: yc = (yf + yb) * silu(z)
// ------------------------------------------------------------------
__global__ __launch_bounds__(256) void combine_k(const float* __restrict__ yf,
                                                 const float* __restrict__ yb,
                                                 const float* __restrict__ z,
                                                 float* __restrict__ yc) {
    int idx = blockIdx.x * 256 + threadIdx.x;
    if (idx >= ROWS * EDIM) return;
    yc[idx] = (yf[idx] + yb[idx]) * silu_f(z[idx]);
}

// ------------------------------------------------------------------
static inline void gemm(hipStream_t s, const float* A, const float* W, const float* b1,
                        const float* b2, const float* resid, float* C,
                        int M, int N, int K) {
    dim3 g(N / BN, (M + BM - 1) / BM);
    gemm_k<<<g, 256, 0, s>>>(A, W, b1, b2, resid, C, M, N, K);
}

extern "C" void kernel_launch(void* const* d_in, const int* in_sizes, int n_in,
                              void* d_out, int out_size, void* d_ws, size_t ws_size,
                              hipStream_t stream) {
    const float* img     = (const float*)d_in[0];
    const float* patch_w = (const float*)d_in[1];
    const float* patch_b = (const float*)d_in[2];
    const float* cls     = (const float*)d_in[3];
    const float* pos     = (const float*)d_in[4];
    const float* ln_g    = (const float*)d_in[5];
    const float* ln_b    = (const float*)d_in[6];
    const float* Wx  = (const float*)d_in[7];  const float* bx  = (const float*)d_in[8];
    const float* Wz  = (const float*)d_in[9];  const float* bz  = (const float*)d_in[10];
    const float* cwf = (const float*)d_in[11]; const float* cbf = (const float*)d_in[12];
    const float* cwb = (const float*)d_in[13]; const float* cbb = (const float*)d_in[14];
    const float* WBf = (const float*)d_in[15]; const float* bBf = (const float*)d_in[16];
    const float* WCf = (const float*)d_in[17]; const float* bCf = (const float*)d_in[18];
    const float* WDf = (const float*)d_in[19]; const float* bDf = (const float*)d_in[20];
    const float* Af  = (const float*)d_in[21]; const float* dbf = (const float*)d_in[22];
    const float* WBb = (const float*)d_in[23]; const float* bBb = (const float*)d_in[24];
    const float* WCb = (const float*)d_in[25]; const float* bCb = (const float*)d_in[26];
    const float* WDb = (const float*)d_in[27]; const float* bDb = (const float*)d_in[28];
    const float* Ab  = (const float*)d_in[29]; const float* dbb = (const float*)d_in[30];
    const float* Wout= (const float*)d_in[31]; const float* bout= (const float*)d_in[32];
    const float* ng  = (const float*)d_in[33]; const float* nb  = (const float*)d_in[34];

    float* ws = (float*)d_ws;
    float* xA  = ws;
    float* xB  = xA + (size_t)ROWS * DDIM;
    float* xn  = xB + (size_t)ROWS * DDIM;
    float* xp  = xn + (size_t)ROWS * DDIM;
    float* zb  = xp + (size_t)ROWS * EDIM;
    float* xfb = zb + (size_t)ROWS * EDIM;
    float* xbb = xfb + (size_t)ROWS * EDIM;
    float* yfb = xbb + (size_t)ROWS * EDIM;
    float* ybb = yfb + (size_t)ROWS * EDIM;
    float* ycb = ybb + (size_t)ROWS * EDIM;
    float* dlt = ycb + (size_t)ROWS * EDIM;
    float* Bmb = dlt + (size_t)ROWS * EDIM;          // ROWS*ENDIM
    float* Cmb = Bmb + (size_t)ROWS * ENDIM;
    // patchify scratch aliases the (not-yet-needed) Bm buffer
    float* patches = Bmb;                             // PROWS*PATCH_K
    float* xemb    = Bmb + (size_t)PROWS * PATCH_K;   // PROWS*DDIM

    // --- patch embedding ---
    patchify_k<<<(PROWS * PATCH_K + 255) / 256, 256, 0, stream>>>(img, patches);
    gemm(stream, patches, patch_w, patch_b, nullptr, nullptr, xemb, PROWS, DDIM, PATCH_K);
    assemble_k<<<(ROWS * DDIM + 255) / 256, 256, 0, stream>>>(xemb, cls, pos, xA);

    float* cur = xA; float* nxt = xB;
    for (int i = 0; i < LLAYERS; ++i) {
        layernorm_k<<<(ROWS + 3) / 4, 256, 0, stream>>>(cur, ln_g + i * DDIM, ln_b + i * DDIM, xn, ROWS);
        gemm(stream, xn, Wx + (size_t)i * DDIM * EDIM, bx + i * EDIM, nullptr, nullptr, xp, ROWS, EDIM, DDIM);
        gemm(stream, xn, Wz + (size_t)i * DDIM * EDIM, bz + i * EDIM, nullptr, nullptr, zb, ROWS, EDIM, DDIM);
        dwconv_k<<<(ROWS * EDIM + 255) / 256, 256, 0, stream>>>(xp, cwf + i * EDIM * 3, cbf + i * EDIM,
                                                                cwb + i * EDIM * 3, cbb + i * EDIM, xfb, xbb);
        // forward branch (dlt holds RAW pre-softplus values)
        gemm(stream, xfb, WBf + (size_t)i * EDIM * ENDIM, bBf + i * ENDIM, nullptr, nullptr, Bmb, ROWS, ENDIM, EDIM);
        gemm(stream, xfb, WCf + (size_t)i * EDIM * ENDIM, bCf + i * ENDIM, nullptr, nullptr, Cmb, ROWS, ENDIM, EDIM);
        gemm(stream, xfb, WDf + (size_t)i * EDIM * EDIM, bDf + i * EDIM, dbf + i * EDIM, nullptr, dlt, ROWS, EDIM, EDIM);
        ssm_scan_k<<<(BATCH * EDIM * NSTATE) / 256, 256, 0, stream>>>(Bmb, Cmb, dlt, xfb, Af + i * EDIM * NSTATE, yfb);
        // backward branch
        gemm(stream, xbb, WBb + (size_t)i * EDIM * ENDIM, bBb + i * ENDIM, nullptr, nullptr, Bmb, ROWS, ENDIM, EDIM);
        gemm(stream, xbb, WCb + (size_t)i * EDIM * ENDIM, bCb + i * ENDIM, nullptr, nullptr, Cmb, ROWS, ENDIM, EDIM);
        gemm(stream, xbb, WDb + (size_t)i * EDIM * EDIM, bDb + i * EDIM, dbb + i * EDIM, nullptr, dlt, ROWS, EDIM, EDIM);
        ssm_scan_k<<<(BATCH * EDIM * NSTATE) / 256, 256, 0, stream>>>(Bmb, Cmb, dlt, xbb, Ab + i * EDIM * NSTATE, ybb);

        combine_k<<<(ROWS * EDIM + 255) / 256, 256, 0, stream>>>(yfb, ybb, zb, ycb);
        gemm(stream, ycb, Wout + (size_t)i * EDIM * DDIM, bout + i * DDIM, nullptr, cur, nxt, ROWS, DDIM, EDIM);
        float* t = cur; cur = nxt; nxt = t;
    }
    layernorm_k<<<(ROWS + 3) / 4, 256, 0, stream>>>(cur, ng, nb, (float*)d_out, ROWS);
}